// Round 9
// baseline (413.740 us; speedup 1.0000x reference)
//
#include <hip/hip_runtime.h>

typedef short short8 __attribute__((ext_vector_type(8)));
typedef float f32x4 __attribute__((ext_vector_type(4)));
typedef unsigned long long u64;

#define NE 1024
#define D 64
#define HW 4096
#define NTOK 65536
#define MARGIN 3.0e-3f
#define FLT_MAX_F 3.402823466e+38f

// ws (<=262KB, proven safe): bn f32[1024]@0 ; ebf u16[65536]@4096 ; win u16[65536]@135168
#define WS_BN  0
#define WS_EBF 4096
#define WS_WIN 135168
// d_out overlay (16MB, fully overwritten by k4_gather):
//   esc_cnt u32 @0 ; esc u32[65536] @4096 ;
//   cm1 f32[8*65536] @270336 ; cm2 f32[8*65536] @2367488 ; ca1 u16[8*65536] @4464640

__device__ __forceinline__ unsigned short f2bf(float f) {   // RNE f32->bf16
    unsigned u = __float_as_uint(f);
    return (unsigned short)((u + 0x7fffu + ((u >> 16) & 1u)) >> 16);
}

// numpy pairwise sum of squares, n=64 (frozen — exact since R2)
__device__ __forceinline__ float np_sum64_sq(const float* v) {
    float s[8];
#pragma unroll
    for (int j = 0; j < 8; ++j) s[j] = __fmul_rn(v[j], v[j]);
#pragma unroll
    for (int i = 8; i < 64; i += 8) {
#pragma unroll
        for (int j = 0; j < 8; ++j)
            s[j] = __fadd_rn(s[j], __fmul_rn(v[i + j], v[i + j]));
    }
    return __fadd_rn(__fadd_rn(__fadd_rn(s[0], s[1]), __fadd_rn(s[2], s[3])),
                     __fadd_rn(__fadd_rn(s[4], s[5]), __fadd_rn(s[6], s[7])));
}

__global__ __launch_bounds__(256) void kP_prep(
        const float* __restrict__ cb, float* __restrict__ bn,
        unsigned short* __restrict__ ebf, unsigned* __restrict__ esc_cnt) {
    const int gid = blockIdx.x * 256 + threadIdx.x;   // 65536 threads
    ebf[gid] = f2bf(cb[gid]);
    if (gid == 0) *esc_cnt = 0u;
    if (gid < NE) {
        float row[D];
        const float4* r4 = reinterpret_cast<const float4*>(cb + (size_t)gid * D);
#pragma unroll
        for (int i = 0; i < 16; ++i) {
            float4 v = r4[i];
            row[4*i+0] = v.x; row[4*i+1] = v.y; row[4*i+2] = v.z; row[4*i+3] = v.w;
        }
        bn[gid] = np_sum64_sq(row);
    }
}

// merge two (v1,i1,v2) top-2 states across lanes (commutative, tie -> min idx)
#define MERGE(v1, i1, v2, off) {                                          \
    float ov1 = __shfl_xor(v1, off);                                      \
    int   oi1 = __shfl_xor(i1, off);                                      \
    float ov2 = __shfl_xor(v2, off);                                      \
    float nv2 = fminf(fmaxf(v1, ov1), fminf(v2, ov2));                    \
    int   ni  = (ov1 < v1) ? oi1 : ((v1 < ov1) ? i1 : (i1 < oi1 ? i1 : oi1)); \
    v1 = fminf(v1, ov1); v2 = nv2; i1 = ni; }

__global__ __launch_bounds__(256, 4) void k1_score(
        const float* __restrict__ in, const unsigned short* __restrict__ ebf,
        const float* __restrict__ bn_g, float* __restrict__ cm1,
        float* __restrict__ cm2, unsigned short* __restrict__ ca1) {
    __shared__ unsigned short ebq[128 * 64];   // 16 KiB, XOR-swizzled (proven)
    __shared__ float sbn[128];

    // XCD-contiguous: XCD x gets token-groups [64x,64x+64), all 8 chunks
    const int sw  = (blockIdx.x & 7) * 512 + (blockIdx.x >> 3);
    const int tg  = sw >> 3;
    const int c   = sw & 7;
    const int tid  = threadIdx.x;
    const int lane = tid & 63, w = tid >> 6;
    const int lcol = lane & 15, lhi = lane >> 4, lrow = lhi * 4;
    const int tokw = tg * 128 + w * 32;

    if (tid < 128) sbn[tid] = bn_g[c * 128 + tid];
    const char* src = (const char*)(ebf + (size_t)c * 128 * 64);
#pragma unroll
    for (int i = 0; i < 4; ++i) {
        int L = (tid + i * 256) * 16;
        int row = L >> 7, wi = L & 127;
        int4 v = *(const int4*)(src + L);
        *(int4*)((char*)ebq + row * 128 + (wi ^ ((row & 7) << 4))) = v;
    }
    // rebuild B fragments from input (frozen layout; L2-local via XCD swizzle)
    const int b = tokw >> 12, hwb = tokw & 4095;
    const float* xbase = in + (size_t)b * (D * HW);
    const int hw0 = hwb + lcol, hw1 = hw0 + 16;
    const int kb = lhi * 8;
    short8 B00, B01, B10, B11;
    {
        const float* p;
        p = xbase + (size_t)kb * HW + hw0;
#pragma unroll
        for (int j = 0; j < 8; ++j) B00[j] = (short)f2bf(p[(size_t)j * HW]);
        p = xbase + (size_t)(kb + 32) * HW + hw0;
#pragma unroll
        for (int j = 0; j < 8; ++j) B01[j] = (short)f2bf(p[(size_t)j * HW]);
        p = xbase + (size_t)kb * HW + hw1;
#pragma unroll
        for (int j = 0; j < 8; ++j) B10[j] = (short)f2bf(p[(size_t)j * HW]);
        p = xbase + (size_t)(kb + 32) * HW + hw1;
#pragma unroll
        for (int j = 0; j < 8; ++j) B11[j] = (short)f2bf(p[(size_t)j * HW]);
    }
    __syncthreads();

    const int swz   = (lcol & 7) << 4;
    const int aoff0 = lcol * 128 + ((lhi * 16) ^ swz);
    const int aoff1 = lcol * 128 + ((64 + lhi * 16) ^ swz);

    // single pass: per-token per-chunk top-2 (value,argmin,value2) in registers
    float a1v = FLT_MAX_F, a2v = FLT_MAX_F; int a1i = 0;
    float b1v = FLT_MAX_F, b2v = FLT_MAX_F; int b1i = 0;
#pragma unroll
    for (int ct = 0; ct < 8; ++ct) {
        const char* lp = (const char*)ebq + ct * 2048;
        short8 A0 = *(const short8*)(lp + aoff0);
        short8 A1 = *(const short8*)(lp + aoff1);
        f32x4 bnv = *(const f32x4*)(sbn + ct * 16 + lrow);
        f32x4 acc = {0.f, 0.f, 0.f, 0.f};
        acc = __builtin_amdgcn_mfma_f32_16x16x32_bf16(A0, B00, acc, 0, 0, 0);
        acc = __builtin_amdgcn_mfma_f32_16x16x32_bf16(A1, B01, acc, 0, 0, 0);
        f32x4 ac2 = {0.f, 0.f, 0.f, 0.f};
        ac2 = __builtin_amdgcn_mfma_f32_16x16x32_bf16(A0, B10, ac2, 0, 0, 0);
        ac2 = __builtin_amdgcn_mfma_f32_16x16x32_bf16(A1, B11, ac2, 0, 0, 0);
        const int kg = c * 128 + ct * 16 + lrow;
#pragma unroll
        for (int r = 0; r < 4; ++r) {
            float t0 = __fmaf_rn(-2.0f, acc[r], bnv[r]);
            bool lt0 = t0 < a1v;
            a2v = lt0 ? a1v : fminf(a2v, t0);
            a1i = lt0 ? (kg + r) : a1i;
            a1v = lt0 ? t0 : a1v;
            float t1 = __fmaf_rn(-2.0f, ac2[r], bnv[r]);
            bool lt1 = t1 < b1v;
            b2v = lt1 ? b1v : fminf(b2v, t1);
            b1i = lt1 ? (kg + r) : b1i;
            b1v = lt1 ? t1 : b1v;
        }
    }
    MERGE(a1v, a1i, a2v, 16); MERGE(a1v, a1i, a2v, 32);
    MERGE(b1v, b1i, b2v, 16); MERGE(b1v, b1i, b2v, 32);

    // coalesced stores, no atomics
    const int base = c * NTOK + tokw + lcol;
    if (lhi == 0) {
        cm1[base] = a1v; cm2[base] = a2v; ca1[base] = (unsigned short)a1i;
    } else if (lhi == 1) {
        cm1[base + 16] = b1v; cm2[base + 16] = b2v; ca1[base + 16] = (unsigned short)b1i;
    }
}

// thread per token: decide from per-chunk top-2; exact-score stored candidates
__global__ __launch_bounds__(256, 4) void k2_decide(
        const float* __restrict__ in, const float* __restrict__ cb,
        const float* __restrict__ bn, const float* __restrict__ cm1,
        const float* __restrict__ cm2, const unsigned short* __restrict__ ca1,
        unsigned* __restrict__ esc_cnt, unsigned* __restrict__ esc,
        unsigned short* __restrict__ win) {
    const int tok = blockIdx.x * 256 + threadIdx.x;
    float c1[8];
    float m = FLT_MAX_F;
#pragma unroll
    for (int c = 0; c < 8; ++c) { c1[c] = cm1[c * NTOK + tok]; m = fminf(m, c1[c]); }
    const float thr = m + MARGIN;
    bool e = false;
#pragma unroll
    for (int c = 0; c < 8; ++c) e = e || (cm2[c * NTOK + tok] <= thr);
    if (e) {                                   // chunk with >=2 near-min codes -> k3
        unsigned p = atomicAdd(esc_cnt, 1u);
        esc[p] = (unsigned)tok;
        return;
    }
    const int b = tok >> 12, hw = tok & 4095;
    const float* x = in + (size_t)b * (D * HW) + hw;
    float xv[D];
#pragma unroll
    for (int d = 0; d < D; ++d) xv[d] = x[(size_t)d * HW];   // coalesced across wave
    const float a = np_sum64_sq(xv);                          // frozen
    u64 best = ~0ull;
#pragma unroll
    for (int c = 0; c < 8; ++c) {
        if (c1[c] <= thr) {
            const int k = ca1[c * NTOK + tok];
            const float* er = cb + (size_t)k * D;
            float dot = 0.f;                                  // frozen: seq asc d
#pragma unroll
            for (int d = 0; d < 64; ++d) dot = __fmaf_rn(xv[d], er[d], dot);
            float qv = __fsub_rn(__fadd_rn(a, bn[k]), __fmul_rn(2.0f, dot));  // frozen
            u64 key = (((u64)__float_as_uint(qv)) << 32) | (unsigned)k;
            best = best < key ? best : key;    // lexicographic (q,k) = np argmin
        }
    }
    win[tok] = (unsigned short)(best & 0x3FFull);
}

// wave per escalated token: exact-scan all flagged chunks (cm1 <= thr)
__global__ __launch_bounds__(256, 4) void k3_escalate(
        const float* __restrict__ in, const float* __restrict__ cb,
        const float* __restrict__ bn, const float* __restrict__ cm1,
        const unsigned* __restrict__ esc_cnt, const unsigned* __restrict__ esc,
        unsigned short* __restrict__ win) {
    const int lane = threadIdx.x & 63;
    const int wid  = (blockIdx.x * 256 + threadIdx.x) >> 6;
    const int nw   = (gridDim.x * 256) >> 6;
    const unsigned n = *esc_cnt;
    for (unsigned i = wid; i < n; i += nw) {
        const int tok = (int)esc[i];
        const int b = tok >> 12, hw = tok & 4095;
        float c1[8];
        float m = FLT_MAX_F;
#pragma unroll
        for (int c = 0; c < 8; ++c) { c1[c] = cm1[c * NTOK + tok]; m = fminf(m, c1[c]); }
        const float thr = m + MARGIN;
        const float xl = in[(size_t)b * (D * HW) + (size_t)lane * HW + hw]; // lane d = x_d
        // 'a' once per wave, frozen np order via shfl broadcast
        float s0=0.f,s1=0.f,s2=0.f,s3=0.f,s4=0.f,s5=0.f,s6=0.f,s7=0.f;
#pragma unroll
        for (int d = 0; d < 64; ++d) {
            const float xd = __shfl(xl, d);
            const float x2 = __fmul_rn(xd, xd);
            switch (d & 7) {
                case 0: s0 = __fadd_rn(s0, x2); break;
                case 1: s1 = __fadd_rn(s1, x2); break;
                case 2: s2 = __fadd_rn(s2, x2); break;
                case 3: s3 = __fadd_rn(s3, x2); break;
                case 4: s4 = __fadd_rn(s4, x2); break;
                case 5: s5 = __fadd_rn(s5, x2); break;
                case 6: s6 = __fadd_rn(s6, x2); break;
                default: s7 = __fadd_rn(s7, x2); break;
            }
        }
        const float a = __fadd_rn(__fadd_rn(__fadd_rn(s0, s1), __fadd_rn(s2, s3)),
                                  __fadd_rn(__fadd_rn(s4, s5), __fadd_rn(s6, s7)));
        u64 best = ~0ull;
        for (int c = 0; c < 8; ++c) {
            if (c1[c] <= thr) {                     // wave-uniform branch
#pragma unroll
                for (int h = 0; h < 2; ++h) {
                    const int k = c * 128 + h * 64 + lane;
                    const float4* e4 = reinterpret_cast<const float4*>(cb + (size_t)k * D);
                    float4 e[16];
#pragma unroll
                    for (int q = 0; q < 16; ++q) e[q] = e4[q];
                    float dot = 0.f;                // frozen: seq asc d
#pragma unroll
                    for (int d = 0; d < 64; ++d) {
                        const float xd = __shfl(xl, d);
                        const float ed = (d & 3) == 0 ? e[d >> 2].x : (d & 3) == 1 ? e[d >> 2].y
                                       : (d & 3) == 2 ? e[d >> 2].z : e[d >> 2].w;
                        dot = __fmaf_rn(xd, ed, dot);
                    }
                    float qv = __fsub_rn(__fadd_rn(a, bn[k]), __fmul_rn(2.0f, dot)); // frozen
                    u64 key = (((u64)__float_as_uint(qv)) << 32) | (unsigned)k;
                    best = best < key ? best : key;
                }
            }
        }
#pragma unroll
        for (int o = 32; o; o >>= 1) {
            u64 v = __shfl_xor(best, o);
            best = best < v ? best : v;
        }
        if (lane == 0) win[tok] = (unsigned short)(best & 0x3FFull);
    }
}

__global__ __launch_bounds__(256) void k4_gather(
        const float* __restrict__ cb, const unsigned short* __restrict__ win,
        float* __restrict__ out) {
    const int gid = blockIdx.x * 256 + threadIdx.x;   // 262144 threads
    const int tok = gid >> 2, qd = (gid & 3) << 4;
    const int b = tok >> 12, hw = tok & 4095;
    const unsigned k = win[tok];
    const float4* er = reinterpret_cast<const float4*>(cb + (size_t)k * D + qd);
    float* ot = out + (size_t)b * (D * HW) + hw;
#pragma unroll
    for (int i = 0; i < 4; ++i) {
        float4 e = er[i];
        ot[(size_t)(qd + 4*i + 0) * HW] = e.x;
        ot[(size_t)(qd + 4*i + 1) * HW] = e.y;
        ot[(size_t)(qd + 4*i + 2) * HW] = e.z;
        ot[(size_t)(qd + 4*i + 3) * HW] = e.w;
    }
}

extern "C" void kernel_launch(void* const* d_in, const int* in_sizes, int n_in,
                              void* d_out, int out_size, void* d_ws, size_t ws_size,
                              hipStream_t stream) {
    const float* in  = (const float*)d_in[0];
    const float* cb  = (const float*)d_in[1];
    float*       out = (float*)d_out;
    char*        ws  = (char*)d_ws;
    char*        ov  = (char*)d_out;

    float*          bn      = (float*)(ws + WS_BN);
    unsigned short* ebf     = (unsigned short*)(ws + WS_EBF);
    unsigned short* win     = (unsigned short*)(ws + WS_WIN);
    unsigned*       esc_cnt = (unsigned*)(ov + 0);
    unsigned*       esc     = (unsigned*)(ov + 4096);
    float*          cm1     = (float*)(ov + 270336);
    float*          cm2     = (float*)(ov + 2367488);
    unsigned short* ca1     = (unsigned short*)(ov + 4464640);

    hipLaunchKernelGGL(kP_prep,    dim3(256),  dim3(256), 0, stream, cb, bn, ebf, esc_cnt);
    hipLaunchKernelGGL(k1_score,   dim3(4096), dim3(256), 0, stream, in, ebf, bn, cm1, cm2, ca1);
    hipLaunchKernelGGL(k2_decide,  dim3(256),  dim3(256), 0, stream, in, cb, bn, cm1, cm2, ca1, esc_cnt, esc, win);
    hipLaunchKernelGGL(k3_escalate,dim3(512),  dim3(256), 0, stream, in, cb, bn, cm1, esc_cnt, esc, win);
    hipLaunchKernelGGL(k4_gather,  dim3(1024), dim3(256), 0, stream, cb, win, out);
}